// Round 1
// baseline (2571.173 us; speedup 1.0000x reference)
//
#include <hip/hip_runtime.h>

// ---------------------------------------------------------------------------
// RQ-VAE fused pipeline, fp32 baseline.
// Encoder (fp32, precision-critical for argmin) -> residual quantize (fp32)
// -> decoder (fp32 this round; candidate for bf16 MFMA later).
// ---------------------------------------------------------------------------

#define NROWS 65536

// Tiled GEMM: C[M x N] = A[M x K] @ W[N x K]^T + bias, optional ReLU.
// BM=128, BK=32, 256 threads, micro-tile TM x TN per thread.
template<int BM, int BN, int BK, int TM, int TN, bool RELU>
__global__ __launch_bounds__(256)
void gemm_bias_kernel(const float* __restrict__ A, const float* __restrict__ W,
                      const float* __restrict__ bias, float* __restrict__ C,
                      int K, int N)
{
    __shared__ float sA[BK][BM + 4];
    __shared__ float sW[BK][BN + 4];

    const int tid  = threadIdx.x;
    const int row0 = blockIdx.x * BM;
    const int col0 = blockIdx.y * BN;
    const int tx   = tid % (BN / TN);
    const int ty   = tid / (BN / TN);
    const int m0   = ty * TM;
    const int n0   = tx * TN;

    float acc[TM][TN];
#pragma unroll
    for (int i = 0; i < TM; i++)
#pragma unroll
        for (int j = 0; j < TN; j++) acc[i][j] = 0.f;

    const int AF4 = BM * BK / 4;
    const int WF4 = BN * BK / 4;

    for (int k0 = 0; k0 < K; k0 += BK) {
        // stage A tile (transposed into [k][m])
        for (int i = tid; i < AF4; i += 256) {
            int m  = i / (BK / 4);
            int kq = i % (BK / 4);
            float4 v = *(const float4*)(A + (size_t)(row0 + m) * K + k0 + kq * 4);
            sA[kq * 4 + 0][m] = v.x; sA[kq * 4 + 1][m] = v.y;
            sA[kq * 4 + 2][m] = v.z; sA[kq * 4 + 3][m] = v.w;
        }
        // stage W tile (transposed into [k][n])
        for (int i = tid; i < WF4; i += 256) {
            int n  = i / (BK / 4);
            int kq = i % (BK / 4);
            float4 v = *(const float4*)(W + (size_t)(col0 + n) * K + k0 + kq * 4);
            sW[kq * 4 + 0][n] = v.x; sW[kq * 4 + 1][n] = v.y;
            sW[kq * 4 + 2][n] = v.z; sW[kq * 4 + 3][n] = v.w;
        }
        __syncthreads();

#pragma unroll
        for (int kk = 0; kk < BK; kk++) {
            float a[TM], w[TN];
#pragma unroll
            for (int i = 0; i < TM; i += 4)
                *(float4*)&a[i] = *(const float4*)&sA[kk][m0 + i];
#pragma unroll
            for (int j = 0; j < TN; j += 4)
                *(float4*)&w[j] = *(const float4*)&sW[kk][n0 + j];
#pragma unroll
            for (int i = 0; i < TM; i++)
#pragma unroll
                for (int j = 0; j < TN; j++) acc[i][j] += a[i] * w[j];
        }
        __syncthreads();
    }

    // epilogue: bias (+ReLU), vectorized store
#pragma unroll
    for (int i = 0; i < TM; i++) {
        size_t crow = (size_t)(row0 + m0 + i) * N + col0 + n0;
#pragma unroll
        for (int j = 0; j < TN; j += 4) {
            float4 v;
            v.x = acc[i][j + 0] + bias[col0 + n0 + j + 0];
            v.y = acc[i][j + 1] + bias[col0 + n0 + j + 1];
            v.z = acc[i][j + 2] + bias[col0 + n0 + j + 2];
            v.w = acc[i][j + 3] + bias[col0 + n0 + j + 3];
            if (RELU) {
                v.x = fmaxf(v.x, 0.f); v.y = fmaxf(v.y, 0.f);
                v.z = fmaxf(v.z, 0.f); v.w = fmaxf(v.w, 0.f);
            }
            *(float4*)(C + crow + j) = v;
        }
    }
}

// Residual quantizer: one thread per row (64-dim), 4 stages x 256 codes.
// Codebook staged per-stage in two 128-code LDS chunks (keeps static LDS < 64KB).
// d = ||r||^2 + ||e||^2 - 2 r.e  (same expansion as the reference, incl. the
// ||r||^2 shift so fp tie-granularity matches np's argmin).
__global__ __launch_bounds__(256)
void rq_kernel(const float* zin, const float* __restrict__ cb,
               float* xq, float* __restrict__ idxout, float* __restrict__ lossacc)
{
    __shared__ float sE[128][68];
    __shared__ float sN[128];
    __shared__ float sRed[4];

    const int tid = threadIdx.x;
    const size_t row = (size_t)blockIdx.x * 256 + tid;

    float r[64];
    const float4* zr = (const float4*)(zin + row * 64);
#pragma unroll
    for (int i = 0; i < 16; i++) {
        float4 v = zr[i];
        r[i * 4 + 0] = v.x; r[i * 4 + 1] = v.y; r[i * 4 + 2] = v.z; r[i * 4 + 3] = v.w;
    }

    float lsum = 0.f;
    float bidx[4];

    for (int s = 0; s < 4; s++) {
        float best = 3.4e38f;
        int bj = 0;
        // ||r||^2 for this stage (constant shift, matches reference's d)
        float rr = 0.f;
#pragma unroll
        for (int k = 0; k < 64; k++) rr += r[k] * r[k];

        for (int c = 0; c < 2; c++) {
            __syncthreads();  // protect previous chunk's reads before overwrite
            const float4* cbs = (const float4*)(cb + ((size_t)s * 256 + c * 128) * 64);
            for (int i = tid; i < 2048; i += 256) {
                int j = i >> 4, kq = i & 15;
                float4 v = cbs[i];
                sE[j][kq * 4 + 0] = v.x; sE[j][kq * 4 + 1] = v.y;
                sE[j][kq * 4 + 2] = v.z; sE[j][kq * 4 + 3] = v.w;
            }
            __syncthreads();
            if (tid < 128) {
                float nv = 0.f;
#pragma unroll
                for (int k = 0; k < 64; k++) { float e = sE[tid][k]; nv += e * e; }
                sN[tid] = nv;
            }
            __syncthreads();

            for (int j = 0; j < 128; j++) {
                float4 acc = {0.f, 0.f, 0.f, 0.f};
#pragma unroll
                for (int kq = 0; kq < 16; kq++) {
                    float4 e = *(const float4*)&sE[j][kq * 4];  // broadcast read
                    acc.x += r[kq * 4 + 0] * e.x;
                    acc.y += r[kq * 4 + 1] * e.y;
                    acc.z += r[kq * 4 + 2] * e.z;
                    acc.w += r[kq * 4 + 3] * e.w;
                }
                float dot = (acc.x + acc.y) + (acc.z + acc.w);
                float d = rr + sN[j] - 2.f * dot;
                if (d < best) { best = d; bj = c * 128 + j; }
            }
        }

        // fetch winning code from global (LDS chunk may be stale), update residual
        const float4* q4 = (const float4*)(cb + ((size_t)s * 256 + bj) * 64);
#pragma unroll
        for (int i = 0; i < 16; i++) {
            float4 q = q4[i];
            r[i * 4 + 0] -= q.x; r[i * 4 + 1] -= q.y;
            r[i * 4 + 2] -= q.z; r[i * 4 + 3] -= q.w;
        }
#pragma unroll
        for (int k = 0; k < 64; k++) lsum += r[k] * r[k];  // (q-r_old)^2 == r_new^2
        bidx[s] = (float)bj;
    }

    // x_q = z - r_final (in-place over z; same thread owns the row)
    float4* xr = (float4*)(xq + row * 64);
#pragma unroll
    for (int i = 0; i < 16; i++) {
        float4 v = zr[i];
        v.x -= r[i * 4 + 0]; v.y -= r[i * 4 + 1];
        v.z -= r[i * 4 + 2]; v.w -= r[i * 4 + 3];
        xr[i] = v;
    }

    // indices as float (harness reads whole out buffer as fp32); offset is odd,
    // so scalar stores (no 16B-aligned vector store possible)
    idxout[row * 4 + 0] = bidx[0];
    idxout[row * 4 + 1] = bidx[1];
    idxout[row * 4 + 2] = bidx[2];
    idxout[row * 4 + 3] = bidx[3];

    // loss reduction: wave shuffle -> LDS -> one atomic per block
#pragma unroll
    for (int o = 32; o > 0; o >>= 1) lsum += __shfl_down(lsum, o, 64);
    if ((tid & 63) == 0) sRed[tid >> 6] = lsum;
    __syncthreads();
    if (tid == 0) atomicAdd(lossacc, sRed[0] + sRed[1] + sRed[2] + sRed[3]);
}

__global__ void zero_kernel(float* p) { *p = 0.f; }

// rq_loss = 1.25 * total_sq / (4 * B * 64)  ;  4*65536*64 = 16777216
__global__ void finalize_kernel(const float* acc, float* out)
{
    *out = (*acc) * (1.25f / 16777216.f);
}

extern "C" void kernel_launch(void* const* d_in, const int* in_sizes, int n_in,
                              void* d_out, int out_size, void* d_ws, size_t ws_size,
                              hipStream_t stream)
{
    const float* x     = (const float*)d_in[0];
    const float* ew[4] = {(const float*)d_in[1], (const float*)d_in[3],
                          (const float*)d_in[5], (const float*)d_in[7]};
    const float* eb[4] = {(const float*)d_in[2], (const float*)d_in[4],
                          (const float*)d_in[6], (const float*)d_in[8]};
    const float* dw[4] = {(const float*)d_in[9],  (const float*)d_in[11],
                          (const float*)d_in[13], (const float*)d_in[15]};
    const float* db[4] = {(const float*)d_in[10], (const float*)d_in[12],
                          (const float*)d_in[14], (const float*)d_in[16]};
    const float* cb    = (const float*)d_in[17];

    // workspace layout (bytes); decoder aliases dead encoder buffers.
    char* ws = (char*)d_ws;
    float* h1      = (float*)(ws + 0);           // B*512*4 = 134217728
    float* h2      = (float*)(ws + 134217728);   // B*256*4 =  67108864
    float* h3      = (float*)(ws + 201326592);   // B*128*4 =  33554432
    float* z       = (float*)(ws + 234881024);   // B*64*4  =  16777216
    float* lossacc = (float*)(ws + 251658240);   // 4 bytes
    float* d1 = h3;   // B*128 fp32, h3 dead after z
    float* d2 = h2;   // B*256 fp32, h2 dead
    float* d3 = h1;   // B*512 fp32, h1 dead

    float* out      = (float*)d_out;
    float* loss_out = out + 50331648;            // B*768
    float* idx_out  = out + 50331649;

    dim3 blk(256);

    // encoder (fp32 — argmin precision depends on z)
    gemm_bias_kernel<128,128,32,8,8,true ><<<dim3(512,4), blk, 0, stream>>>(x,  ew[0], eb[0], h1, 768, 512);
    gemm_bias_kernel<128,128,32,8,8,true ><<<dim3(512,2), blk, 0, stream>>>(h1, ew[1], eb[1], h2, 512, 256);
    gemm_bias_kernel<128,128,32,8,8,true ><<<dim3(512,1), blk, 0, stream>>>(h2, ew[2], eb[2], h3, 256, 128);
    gemm_bias_kernel<128, 64,32,8,4,false><<<dim3(512,1), blk, 0, stream>>>(h3, ew[3], eb[3], z,  128,  64);

    // residual quantize (z -> x_q in place, indices, loss)
    zero_kernel<<<1, 1, 0, stream>>>(lossacc);
    rq_kernel<<<256, blk, 0, stream>>>(z, cb, z, idx_out, lossacc);
    finalize_kernel<<<1, 1, 0, stream>>>(lossacc, loss_out);

    // decoder
    gemm_bias_kernel<128,128,32,8,8,true ><<<dim3(512,1), blk, 0, stream>>>(z,  dw[0], db[0], d1,  64, 128);
    gemm_bias_kernel<128,128,32,8,8,true ><<<dim3(512,2), blk, 0, stream>>>(d1, dw[1], db[1], d2, 128, 256);
    gemm_bias_kernel<128,128,32,8,8,true ><<<dim3(512,4), blk, 0, stream>>>(d2, dw[2], db[2], d3, 256, 512);
    gemm_bias_kernel<128,128,32,8,8,false><<<dim3(512,6), blk, 0, stream>>>(d3, dw[3], db[3], out, 512, 768);
}

// Round 2
// 1744.784 us; speedup vs baseline: 1.4736x; 1.4736x over previous
//
#include <hip/hip_runtime.h>

// ---------------------------------------------------------------------------
// RQ-VAE: fp32 encoder + fp32 residual-quantize (argmin precision-critical),
// bf16 MFMA decoder (output tolerance ~2% permits bf16 inputs / fp32 accum).
// ---------------------------------------------------------------------------

typedef __attribute__((ext_vector_type(8))) __bf16 bf16x8;
typedef __attribute__((ext_vector_type(4))) float f32x4;

__device__ inline unsigned short f2bf(float f) {
    unsigned int u = __float_as_uint(f);
    unsigned int r = (u + 0x7FFF + ((u >> 16) & 1)) >> 16;  // RNE
    return (unsigned short)r;
}

// ---------------------------------------------------------------------------
// fp32 tiled GEMM (encoder): C[MxN] = A[MxK] @ W[NxK]^T + bias, optional ReLU
// ---------------------------------------------------------------------------
template<int BM, int BN, int BK, int TM, int TN, bool RELU>
__global__ __launch_bounds__(256)
void gemm_bias_kernel(const float* __restrict__ A, const float* __restrict__ W,
                      const float* __restrict__ bias, float* __restrict__ C,
                      int K, int N)
{
    __shared__ float sA[BK][BM + 4];
    __shared__ float sW[BK][BN + 4];

    const int tid  = threadIdx.x;
    const int row0 = blockIdx.x * BM;
    const int col0 = blockIdx.y * BN;
    const int tx   = tid % (BN / TN);
    const int ty   = tid / (BN / TN);
    const int m0   = ty * TM;
    const int n0   = tx * TN;

    float acc[TM][TN];
#pragma unroll
    for (int i = 0; i < TM; i++)
#pragma unroll
        for (int j = 0; j < TN; j++) acc[i][j] = 0.f;

    const int AF4 = BM * BK / 4;
    const int WF4 = BN * BK / 4;

    for (int k0 = 0; k0 < K; k0 += BK) {
        for (int i = tid; i < AF4; i += 256) {
            int m  = i / (BK / 4);
            int kq = i % (BK / 4);
            float4 v = *(const float4*)(A + (size_t)(row0 + m) * K + k0 + kq * 4);
            sA[kq * 4 + 0][m] = v.x; sA[kq * 4 + 1][m] = v.y;
            sA[kq * 4 + 2][m] = v.z; sA[kq * 4 + 3][m] = v.w;
        }
        for (int i = tid; i < WF4; i += 256) {
            int n  = i / (BK / 4);
            int kq = i % (BK / 4);
            float4 v = *(const float4*)(W + (size_t)(col0 + n) * K + k0 + kq * 4);
            sW[kq * 4 + 0][n] = v.x; sW[kq * 4 + 1][n] = v.y;
            sW[kq * 4 + 2][n] = v.z; sW[kq * 4 + 3][n] = v.w;
        }
        __syncthreads();

#pragma unroll
        for (int kk = 0; kk < BK; kk++) {
            float a[TM], w[TN];
#pragma unroll
            for (int i = 0; i < TM; i += 4)
                *(float4*)&a[i] = *(const float4*)&sA[kk][m0 + i];
#pragma unroll
            for (int j = 0; j < TN; j += 4)
                *(float4*)&w[j] = *(const float4*)&sW[kk][n0 + j];
#pragma unroll
            for (int i = 0; i < TM; i++)
#pragma unroll
                for (int j = 0; j < TN; j++) acc[i][j] += a[i] * w[j];
        }
        __syncthreads();
    }

#pragma unroll
    for (int i = 0; i < TM; i++) {
        size_t crow = (size_t)(row0 + m0 + i) * N + col0 + n0;
#pragma unroll
        for (int j = 0; j < TN; j += 4) {
            float4 v;
            v.x = acc[i][j + 0] + bias[col0 + n0 + j + 0];
            v.y = acc[i][j + 1] + bias[col0 + n0 + j + 1];
            v.z = acc[i][j + 2] + bias[col0 + n0 + j + 2];
            v.w = acc[i][j + 3] + bias[col0 + n0 + j + 3];
            if (RELU) {
                v.x = fmaxf(v.x, 0.f); v.y = fmaxf(v.y, 0.f);
                v.z = fmaxf(v.z, 0.f); v.w = fmaxf(v.w, 0.f);
            }
            *(float4*)(C + crow + j) = v;
        }
    }
}

// ---------------------------------------------------------------------------
// bf16 MFMA GEMM (decoder): C[MxN] = A[MxK](bf16) @ W[NxK]^T(bf16) + bias(f32)
// m97 structure: 128x128 tile, BK=32, global_load_lds width-16 staging,
// 4 waves in 2x2, each wave 4x4 grid of 16x16x32 MFMAs.
// ---------------------------------------------------------------------------
template<bool RELU, bool OUTBF16>
__global__ __launch_bounds__(256)
void mfma_gemm_kernel(const unsigned short* __restrict__ A,
                      const unsigned short* __restrict__ W,
                      const float* __restrict__ bias, void* __restrict__ Cout,
                      int K, int N)
{
    __shared__ unsigned short sA[128 * 32];   // [row][k], k-contig, no pad
    __shared__ unsigned short sB[128 * 32];

    const int tid   = threadIdx.x;
    const int lane  = tid & 63;
    const int wv    = tid >> 6;
    const int row0  = blockIdx.x * 128;
    const int col0  = blockIdx.y * 128;
    const int m_off = (wv >> 1) * 64;
    const int n_off = (wv & 1) * 64;

    f32x4 acc[4][4];
#pragma unroll
    for (int i = 0; i < 4; i++)
#pragma unroll
        for (int j = 0; j < 4; j++) acc[i][j] = (f32x4){0.f, 0.f, 0.f, 0.f};

    const int lr = lane >> 2;        // row within 16-row chunk
    const int lk = (lane & 3) * 8;   // k element offset (8 bf16 = 16B)

    for (int k0 = 0; k0 < K; k0 += 32) {
        __syncthreads();  // protect previous iter's fragment reads
#pragma unroll
        for (int c = 0; c < 2; c++) {
            int ch = wv + c * 4;               // chunk 0..7 (16 rows each)
            int r  = ch * 16 + lr;
            const unsigned short* ga = A + (size_t)(row0 + r) * K + k0 + lk;
            const unsigned short* gb = W + (size_t)(col0 + r) * K + k0 + lk;
            // LDS dest: wave-uniform base + lane*16B (required layout)
            __builtin_amdgcn_global_load_lds(
                (__attribute__((address_space(1))) void*)ga,
                (__attribute__((address_space(3))) void*)(sA + ch * 512 + lane * 8),
                16, 0, 0);
            __builtin_amdgcn_global_load_lds(
                (__attribute__((address_space(1))) void*)gb,
                (__attribute__((address_space(3))) void*)(sB + ch * 512 + lane * 8),
                16, 0, 0);
        }
        __syncthreads();  // drains vmcnt (global_load_lds) before reads

        bf16x8 af[4], bf[4];
#pragma unroll
        for (int i = 0; i < 4; i++) {
            af[i] = *(const bf16x8*)(sA + (m_off + i * 16 + (lane & 15)) * 32 + (lane >> 4) * 8);
            bf[i] = *(const bf16x8*)(sB + (n_off + i * 16 + (lane & 15)) * 32 + (lane >> 4) * 8);
        }
#pragma unroll
        for (int mi = 0; mi < 4; mi++)
#pragma unroll
            for (int ni = 0; ni < 4; ni++)
                acc[mi][ni] = __builtin_amdgcn_mfma_f32_16x16x32_bf16(
                    af[mi], bf[ni], acc[mi][ni], 0, 0, 0);
    }

    // epilogue: C/D layout col=lane&15, row=(lane>>4)*4+reg  [m89/m91]
    const int crow = row0 + m_off + (lane >> 4) * 4;
    const int ccol = col0 + n_off + (lane & 15);
#pragma unroll
    for (int ni = 0; ni < 4; ni++) {
        int col = ccol + ni * 16;
        float b = bias[col];
#pragma unroll
        for (int mi = 0; mi < 4; mi++) {
#pragma unroll
            for (int r = 0; r < 4; r++) {
                float v = acc[mi][ni][r] + b;
                if (RELU) v = fmaxf(v, 0.f);
                size_t off = (size_t)(crow + mi * 16 + r) * N + col;
                if (OUTBF16) ((unsigned short*)Cout)[off] = f2bf(v);
                else         ((float*)Cout)[off] = v;
            }
        }
    }
}

// ---------------------------------------------------------------------------
// Residual quantizer (fp32, unchanged math) + bf16 x_q emission for decoder
// ---------------------------------------------------------------------------
__global__ __launch_bounds__(256)
void rq_kernel(const float* zin, const float* __restrict__ cb,
               unsigned short* __restrict__ xqbf, float* __restrict__ idxout,
               float* __restrict__ lossacc)
{
    __shared__ float sE[128][68];
    __shared__ float sN[128];
    __shared__ float sRed[4];

    const int tid = threadIdx.x;
    const size_t row = (size_t)blockIdx.x * 256 + tid;

    float r[64];
    const float4* zr = (const float4*)(zin + row * 64);
#pragma unroll
    for (int i = 0; i < 16; i++) {
        float4 v = zr[i];
        r[i * 4 + 0] = v.x; r[i * 4 + 1] = v.y; r[i * 4 + 2] = v.z; r[i * 4 + 3] = v.w;
    }

    float lsum = 0.f;
    float bidx[4];

    for (int s = 0; s < 4; s++) {
        float best = 3.4e38f;
        int bj = 0;
        float rr = 0.f;
#pragma unroll
        for (int k = 0; k < 64; k++) rr += r[k] * r[k];

        for (int c = 0; c < 2; c++) {
            __syncthreads();
            const float4* cbs = (const float4*)(cb + ((size_t)s * 256 + c * 128) * 64);
            for (int i = tid; i < 2048; i += 256) {
                int j = i >> 4, kq = i & 15;
                float4 v = cbs[i];
                sE[j][kq * 4 + 0] = v.x; sE[j][kq * 4 + 1] = v.y;
                sE[j][kq * 4 + 2] = v.z; sE[j][kq * 4 + 3] = v.w;
            }
            __syncthreads();
            if (tid < 128) {
                float nv = 0.f;
#pragma unroll
                for (int k = 0; k < 64; k++) { float e = sE[tid][k]; nv += e * e; }
                sN[tid] = nv;
            }
            __syncthreads();

            for (int j = 0; j < 128; j++) {
                float4 accv = {0.f, 0.f, 0.f, 0.f};
#pragma unroll
                for (int kq = 0; kq < 16; kq++) {
                    float4 e = *(const float4*)&sE[j][kq * 4];
                    accv.x += r[kq * 4 + 0] * e.x;
                    accv.y += r[kq * 4 + 1] * e.y;
                    accv.z += r[kq * 4 + 2] * e.z;
                    accv.w += r[kq * 4 + 3] * e.w;
                }
                float dot = (accv.x + accv.y) + (accv.z + accv.w);
                float d = rr + sN[j] - 2.f * dot;
                if (d < best) { best = d; bj = c * 128 + j; }
            }
        }

        const float4* q4 = (const float4*)(cb + ((size_t)s * 256 + bj) * 64);
#pragma unroll
        for (int i = 0; i < 16; i++) {
            float4 q = q4[i];
            r[i * 4 + 0] -= q.x; r[i * 4 + 1] -= q.y;
            r[i * 4 + 2] -= q.z; r[i * 4 + 3] -= q.w;
        }
#pragma unroll
        for (int k = 0; k < 64; k++) lsum += r[k] * r[k];
        bidx[s] = (float)bj;
    }

    // x_q = z - r_final, emitted as bf16 for the MFMA decoder
    ushort4* xb = (ushort4*)(xqbf + row * 64);
#pragma unroll
    for (int i = 0; i < 16; i++) {
        float4 v = zr[i];
        ushort4 o;
        o.x = f2bf(v.x - r[i * 4 + 0]);
        o.y = f2bf(v.y - r[i * 4 + 1]);
        o.z = f2bf(v.z - r[i * 4 + 2]);
        o.w = f2bf(v.w - r[i * 4 + 3]);
        xb[i] = o;
    }

    idxout[row * 4 + 0] = bidx[0];
    idxout[row * 4 + 1] = bidx[1];
    idxout[row * 4 + 2] = bidx[2];
    idxout[row * 4 + 3] = bidx[3];

#pragma unroll
    for (int o = 32; o > 0; o >>= 1) lsum += __shfl_down(lsum, o, 64);
    if ((tid & 63) == 0) sRed[tid >> 6] = lsum;
    __syncthreads();
    if (tid == 0) atomicAdd(lossacc, sRed[0] + sRed[1] + sRed[2] + sRed[3]);
}

__global__ void zero_kernel(float* p) { *p = 0.f; }

__global__ void finalize_kernel(const float* acc, float* out)
{
    *out = (*acc) * (1.25f / 16777216.f);
}

__global__ void cast_f2b_kernel(const float* __restrict__ in,
                                unsigned short* __restrict__ out, int n4)
{
    int i = blockIdx.x * 256 + threadIdx.x;
    if (i < n4) {
        float4 v = ((const float4*)in)[i];
        ushort4 o;
        o.x = f2bf(v.x); o.y = f2bf(v.y); o.z = f2bf(v.z); o.w = f2bf(v.w);
        ((ushort4*)out)[i] = o;
    }
}

extern "C" void kernel_launch(void* const* d_in, const int* in_sizes, int n_in,
                              void* d_out, int out_size, void* d_ws, size_t ws_size,
                              hipStream_t stream)
{
    const float* x     = (const float*)d_in[0];
    const float* ew[4] = {(const float*)d_in[1], (const float*)d_in[3],
                          (const float*)d_in[5], (const float*)d_in[7]};
    const float* eb[4] = {(const float*)d_in[2], (const float*)d_in[4],
                          (const float*)d_in[6], (const float*)d_in[8]};
    const float* dw[4] = {(const float*)d_in[9],  (const float*)d_in[11],
                          (const float*)d_in[13], (const float*)d_in[15]};
    const float* db[4] = {(const float*)d_in[10], (const float*)d_in[12],
                          (const float*)d_in[14], (const float*)d_in[16]};
    const float* cb    = (const float*)d_in[17];

    // workspace layout (bytes)
    char* ws = (char*)d_ws;
    float* h1      = (float*)(ws + 0);           // B*512*4 = 134217728 (encoder)
    float* h2      = (float*)(ws + 134217728);   // B*256*4
    float* h3      = (float*)(ws + 201326592);   // B*128*4
    float* z       = (float*)(ws + 234881024);   // B*64*4
    float* lossacc = (float*)(ws + 251658240);

    // decoder bf16 buffers alias h1's region (dead after encoder L2)
    unsigned short* xq_bf = (unsigned short*)(ws + 0);          // B*64*2  = 8388608
    unsigned short* d1    = (unsigned short*)(ws + 8388608);    // B*128*2 = 16777216
    unsigned short* d2    = (unsigned short*)(ws + 25165824);   // B*256*2 = 33554432
    unsigned short* d3    = (unsigned short*)(ws + 58720256);   // B*512*2 = 67108864
    unsigned short* wb0   = (unsigned short*)(ws + 125829120);  // 128*64*2
    unsigned short* wb1   = wb0 + 128 * 64;                     // 256*128*2
    unsigned short* wb2   = wb1 + 256 * 128;                    // 512*256*2
    unsigned short* wb3   = wb2 + 512 * 256;                    // 768*512*2 (ends < 134217728)

    float* out      = (float*)d_out;
    float* loss_out = out + 50331648;
    float* idx_out  = out + 50331649;

    dim3 blk(256);

    // encoder (fp32 — argmin precision depends on z)
    gemm_bias_kernel<128,128,32,8,8,true ><<<dim3(512,4), blk, 0, stream>>>(x,  ew[0], eb[0], h1, 768, 512);
    gemm_bias_kernel<128,128,32,8,8,true ><<<dim3(512,2), blk, 0, stream>>>(h1, ew[1], eb[1], h2, 512, 256);
    // h1 now dead -> cast decoder weights into its region
    cast_f2b_kernel<<<dim3( 8), blk, 0, stream>>>(dw[0], wb0,  2048);
    cast_f2b_kernel<<<dim3(32), blk, 0, stream>>>(dw[1], wb1,  8192);
    cast_f2b_kernel<<<dim3(128), blk, 0, stream>>>(dw[2], wb2, 32768);
    cast_f2b_kernel<<<dim3(384), blk, 0, stream>>>(dw[3], wb3, 98304);
    gemm_bias_kernel<128,128,32,8,8,true ><<<dim3(512,1), blk, 0, stream>>>(h2, ew[2], eb[2], h3, 256, 128);
    gemm_bias_kernel<128, 64,32,8,4,false><<<dim3(512,1), blk, 0, stream>>>(h3, ew[3], eb[3], z,  128,  64);

    // residual quantize (fp32; emits bf16 x_q, indices, loss)
    zero_kernel<<<1, 1, 0, stream>>>(lossacc);
    rq_kernel<<<256, blk, 0, stream>>>(z, cb, xq_bf, idx_out, lossacc);
    finalize_kernel<<<1, 1, 0, stream>>>(lossacc, loss_out);

    // decoder (bf16 MFMA)
    mfma_gemm_kernel<true, true ><<<dim3(512,1), blk, 0, stream>>>(xq_bf, wb0, db[0], d1,   64, 128);
    mfma_gemm_kernel<true, true ><<<dim3(512,2), blk, 0, stream>>>(d1,    wb1, db[1], d2,  128, 256);
    mfma_gemm_kernel<true, true ><<<dim3(512,4), blk, 0, stream>>>(d2,    wb2, db[2], d3,  256, 512);
    mfma_gemm_kernel<false,false><<<dim3(512,6), blk, 0, stream>>>(d3,    wb3, db[3], out, 512, 768);
}